// Round 19
// baseline (182.825 us; speedup 1.0000x reference)
//
#include <hip/hip_runtime.h>

typedef __bf16 bf16_t;
typedef __bf16 bf16x8 __attribute__((ext_vector_type(8)));
typedef __bf16 bf16x4 __attribute__((ext_vector_type(4)));
typedef float f32x4 __attribute__((ext_vector_type(4)));

#define S_LEN 2048
#define D_EMB 1024
#define NH 16

#define MFMA16(a, b, c) __builtin_amdgcn_mfma_f32_16x16x32_bf16((a), (b), (c), 0, 0, 0)
#define BARRIER()                        \
  asm volatile("" ::: "memory");         \
  __builtin_amdgcn_s_barrier();          \
  asm volatile("" ::: "memory")

__device__ __forceinline__ void gld16(void* lds, const void* g) {
  __builtin_amdgcn_global_load_lds(
      (__attribute__((address_space(1))) void*)(void*)(g),
      (__attribute__((address_space(3))) void*)(lds), 16, 0, 0);
}

__device__ __forceinline__ float exp2_hw(float x) {
  float r;
  asm("v_exp_f32 %0, %1" : "=v"(r) : "v"(x));
  return r;
}

// ---------------- fp32 -> bf16 convert ----------------
__global__ __launch_bounds__(256) void cvt_bf16(const float* __restrict__ in,
                                                bf16_t* __restrict__ out, int n4) {
  int i = blockIdx.x * 256 + threadIdx.x;
  if (i >= n4) return;
  float4 v = ((const float4*)in)[i];
  bf16x4 o;
  o[0] = (bf16_t)v.x; o[1] = (bf16_t)v.y; o[2] = (bf16_t)v.z; o[3] = (bf16_t)v.w;
  ((bf16x4*)out)[i] = o;
}

// ============ QKV GEMM: 8-phase 256^2 template (512 thr, 8 waves 2Mx4N) =========
// qkv[m][e] = sum_k x[m][k]*w_qkv[e][k] + b_qkv[e], scattered per EPI-1 layout.
// Geometry: BM=BN=256, BK=64, per-wave 128x64 (acc[8][4]), kk-major phases with
// B-frag register reuse (ph1/2 read B(kk0/kk1); ph3/4 reuse). LDS 128KB (2 slots).
// Staging units: A in 64-row quarters (1 gld16/thr), W in 128-row halves (2/thr).
// Phase issue plan (iter t: even tile e=2t in slot0 ph1-4, odd o=2t+1 slot1 ph5-8):
//   ph1: Aq0,Aq2(o)->s1   ph2: Aq1,Aq3(o)->s1   ph3: Wlo(e+2)->s0  ph4: Whi(e+2)->s0
//   ph5: Aq0,Aq2(e+2)     ph6: Aq1,Aq3(e+2)     ph7: Wlo(o+2)->s1  ph8: Whi(o+2)->s1
// Every unit lands >=4 phases before first read (RAW); every overwrite is >=1
// barrier after the region's last read (WAR; kk-major makes W/A-mh0 done by ph2).
// Waits: ph1-top vmcnt(4) (drains tile e, keeps W(o) 2 units); ph5-top vmcnt(4)
// (drains W+Aq(o) and older, keeps Wlo/Whi(e+2)); last iter ph5 uses vmcnt(0).
__global__ __launch_bounds__(512, 2) void gemm_qkv_8p(
    const bf16_t* __restrict__ A, const bf16_t* __restrict__ W,
    const float* __restrict__ bias, bf16_t* __restrict__ outQ) {
  const int K = 1024;
  __shared__ __attribute__((aligned(16))) bf16_t As[2][256 * 64];
  __shared__ __attribute__((aligned(16))) bf16_t Ws[2][256 * 64];
  const int tid = threadIdx.x, lane = tid & 63, wid = tid >> 6;
  const int l15 = lane & 15, lg = lane >> 4;
  const int wm = wid >> 2, wn = wid & 3;
  int lin = blockIdx.x + 12 * blockIdx.y;  // 384 blocks (12 x 32)
  lin = (lin & 7) * 48 + (lin >> 3);       // XCD swizzle (bijective, 384%8==0)
  const int tm = (lin / 12) * 256, tn = (lin % 12) * 256;
  const int q0 = tid * 16;

  // A quarter (64 rows, 8KB): 1 gld16/thread
  auto stAq = [&](int kt, int quad, int slot) {
    int row = q0 >> 7;  // 0..63
    int scb = (q0 & 127) ^ ((row & 7) << 4);
    gld16((char*)As[slot] + quad * 8192 + (q0 & ~1023),
          (const char*)A + ((size_t)(tm + quad * 64 + row) * K + kt * 64) * 2 + scb);
  };
  // W half (128 rows, 16KB): 2 gld16/thread
  auto stWh = [&](int kt, int half, int slot) {
#pragma unroll
    for (int i = 0; i < 2; ++i) {
      int q = q0 + i * 8192;
      int row = q >> 7;  // 0..127
      int scb = (q & 127) ^ ((row & 7) << 4);
      gld16((char*)Ws[slot] + half * 16384 + (q & ~1023),
            (const char*)W + ((size_t)(tn + half * 128 + row) * K + kt * 64) * 2 + scb);
    }
  };
  auto rdA = [&](int slot, int mh, int kk, bf16x8(&af)[4]) {
#pragma unroll
    for (int m2 = 0; m2 < 4; ++m2) {
      int row = wm * 128 + mh * 64 + m2 * 16 + l15;
      af[m2] = *(const bf16x8*)((const char*)As[slot] + row * 128 +
                                ((kk * 64 + lg * 16) ^ ((row & 7) << 4)));
    }
  };
  auto rdB = [&](int slot, int kk, bf16x8(&bf)[4]) {
#pragma unroll
    for (int ni = 0; ni < 4; ++ni) {
      int col = wn * 64 + ni * 16 + l15;
      bf[ni] = *(const bf16x8*)((const char*)Ws[slot] + col * 128 +
                                ((kk * 64 + lg * 16) ^ ((col & 7) << 4)));
    }
  };

  f32x4 acc[8][4] = {};
  bf16x8 af[4], bf0[4], bf1[4];
  auto mm = [&](int mh, bf16x8(&a)[4], bf16x8(&b)[4]) {
    __builtin_amdgcn_s_setprio(1);
#pragma unroll
    for (int m2 = 0; m2 < 4; ++m2)
#pragma unroll
      for (int ni = 0; ni < 4; ++ni)
        acc[mh * 4 + m2][ni] = MFMA16(a[m2], b[ni], acc[mh * 4 + m2][ni]);
    __builtin_amdgcn_s_setprio(0);
  };

  // prologue: tile0 (W halves then A quarters) -> slot0, then W(1) -> slot1
  stWh(0, 0, 0); stWh(0, 1, 0);
  stAq(0, 0, 0); stAq(0, 2, 0); stAq(0, 1, 0); stAq(0, 3, 0);
  stWh(1, 0, 1); stWh(1, 1, 1);

  for (int t = 0; t < 8; ++t) {
    const int e = 2 * t, o = 2 * t + 1;
    // ---- ph1 (e, mh0, kk0)
    asm volatile("s_waitcnt vmcnt(4)" ::: "memory");
    BARRIER();
    stAq(o, 0, 1); stAq(o, 2, 1);
    rdA(0, 0, 0, af); rdB(0, 0, bf0);
    BARRIER();
    mm(0, af, bf0);
    // ---- ph2 (e, mh0, kk1)
    BARRIER();
    stAq(o, 1, 1); stAq(o, 3, 1);
    rdA(0, 0, 1, af); rdB(0, 1, bf1);
    BARRIER();
    mm(0, af, bf1);
    // ---- ph3 (e, mh1, kk0)
    BARRIER();
    if (t < 7) stWh(e + 2, 0, 0);
    rdA(0, 1, 0, af);
    BARRIER();
    mm(1, af, bf0);
    // ---- ph4 (e, mh1, kk1)
    BARRIER();
    if (t < 7) stWh(e + 2, 1, 0);
    rdA(0, 1, 1, af);
    BARRIER();
    mm(1, af, bf1);
    // ---- ph5 (o, mh0, kk0)
    if (t < 7) {
      asm volatile("s_waitcnt vmcnt(4)" ::: "memory");
    } else {
      asm volatile("s_waitcnt vmcnt(0)" ::: "memory");
    }
    BARRIER();
    if (t < 7) { stAq(e + 2, 0, 0); stAq(e + 2, 2, 0); }
    rdA(1, 0, 0, af); rdB(1, 0, bf0);
    BARRIER();
    mm(0, af, bf0);
    // ---- ph6 (o, mh0, kk1)
    BARRIER();
    if (t < 7) { stAq(e + 2, 1, 0); stAq(e + 2, 3, 0); }
    rdA(1, 0, 1, af); rdB(1, 1, bf1);
    BARRIER();
    mm(0, af, bf1);
    // ---- ph7 (o, mh1, kk0)
    BARRIER();
    if (t < 7) stWh(o + 2, 0, 1);
    rdA(1, 1, 0, af);
    BARRIER();
    mm(1, af, bf0);
    // ---- ph8 (o, mh1, kk1)
    BARRIER();
    if (t < 7) stWh(o + 2, 1, 1);
    rdA(1, 1, 1, af);
    BARRIER();
    mm(1, af, bf1);
  }

  // epilogue: qkv scatter (same mapping as EPI-1), rows tm+wm*128+mi*16+lg*4+j,
  // cols tn+wn*64+ni*16+l15. V keys permuted within 32-blocks for attn b128 PV.
#pragma unroll
  for (int mi = 0; mi < 8; ++mi)
#pragma unroll
    for (int ni = 0; ni < 4; ++ni) {
      int e = tn + wn * 64 + ni * 16 + l15;
      float bv = bias[e];
      int h = e / 192;
      int r = e - h * 192;
      int tt = r >> 6, c = r & 63;
#pragma unroll
      for (int j = 0; j < 4; ++j) {
        int m = tm + wm * 128 + mi * 16 + lg * 4 + j;
        int b = m >> 11, s = m & 2047;
        float v = acc[mi][ni][j] + bv;
        if (tt == 0) v *= 0.18033688011112042f;  // (1/sqrt(64)) * log2(e)
        size_t base = ((size_t)(b * NH + h) * 3 + tt) * (size_t)(S_LEN * 64);
        size_t idx;
        if (tt == 2) {
          int rs = s & 31;
          int rp = (((rs >> 2) & 3) << 3) | ((rs >> 4) << 2) | (rs & 3);
          idx = base + (size_t)c * S_LEN + (size_t)((s & ~31) | rp);
        } else {
          idx = base + (size_t)s * 64 + c;
        }
        outQ[idx] = (bf16_t)v;
      }
    }
}

// ---------------- GEMM (round-18 dbuf version; used for out-proj only) ----------
template <int EPI>
__global__ __launch_bounds__(256) void gemm_bt(
    const bf16_t* __restrict__ A, const bf16_t* __restrict__ W,
    const float* __restrict__ bias, float* __restrict__ outF,
    bf16_t* __restrict__ outQ, int M, int N, int K) {
  __shared__ __attribute__((aligned(16))) bf16_t As[2][128 * 64];
  __shared__ __attribute__((aligned(16))) bf16_t Ws[2][128 * 64];
  const int tid = threadIdx.x;
  const int lane = tid & 63;
  const int wid = tid >> 6;
  const int l15 = lane & 15, lg = lane >> 4;
  int lin = blockIdx.x + gridDim.x * blockIdx.y;
  const int nwg = gridDim.x * gridDim.y;
  lin = (lin & 7) * (nwg >> 3) + (lin >> 3);  // XCD swizzle (bijective, nwg%8==0)
  const int tm = (lin / gridDim.x) * 128, tn = (lin % gridDim.x) * 128;
  const int wm = (wid >> 1) * 64, wn = (wid & 1) * 64;
  f32x4 acc[4][4] = {};
  const int q0 = tid * 16;

  auto stage = [&](int k0, int buf) {
#pragma unroll
    for (int i = 0; i < 4; ++i) {
      int q = q0 + i * 4096;
      int row = q >> 7;
      int scb = (q & 127) ^ ((row & 7) << 4);
      gld16((char*)As[buf] + (q & ~1023),
            (const char*)A + ((size_t)(tm + row) * K + k0) * 2 + scb);
      gld16((char*)Ws[buf] + (q & ~1023),
            (const char*)W + ((size_t)(tn + row) * K + k0) * 2 + scb);
    }
  };

  stage(0, 0);
  __syncthreads();

  const int nkt = K >> 6;
  for (int it = 0; it < nkt; ++it) {
    const int cur = it & 1;
    if (it + 1 < nkt) stage((it + 1) << 6, cur ^ 1);
#pragma unroll
    for (int kk = 0; kk < 2; ++kk) {
      const int cb = kk * 64 + lg * 16;
      bf16x8 af[4], bfr[4];
#pragma unroll
      for (int mi = 0; mi < 4; ++mi) {
        int row = wm + mi * 16 + l15;
        af[mi] = *(const bf16x8*)((const char*)As[cur] + row * 128 +
                                  (cb ^ ((row & 7) << 4)));
      }
#pragma unroll
      for (int ni = 0; ni < 4; ++ni) {
        int row = wn + ni * 16 + l15;
        bfr[ni] = *(const bf16x8*)((const char*)Ws[cur] + row * 128 +
                                   (cb ^ ((row & 7) << 4)));
      }
#pragma unroll
      for (int mi = 0; mi < 4; ++mi)
#pragma unroll
        for (int ni = 0; ni < 4; ++ni)
          acc[mi][ni] = MFMA16(af[mi], bfr[ni], acc[mi][ni]);
    }
    if (it + 1 < nkt) __syncthreads();
  }

  if (EPI == 0) {
#pragma unroll
    for (int mi = 0; mi < 4; ++mi)
#pragma unroll
      for (int ni = 0; ni < 4; ++ni) {
        int colg = tn + wn + ni * 16 + l15;
        float bv = bias[colg];
#pragma unroll
        for (int j = 0; j < 4; ++j) {
          int rowg = tm + wm + mi * 16 + lg * 4 + j;
          outF[(size_t)rowg * N + colg] = acc[mi][ni][j] + bv;
        }
      }
  } else {
#pragma unroll
    for (int mi = 0; mi < 4; ++mi)
#pragma unroll
      for (int ni = 0; ni < 4; ++ni) {
        int e = tn + wn + ni * 16 + l15;
        float bv = bias[e];
        int h = e / 192;
        int r = e - h * 192;
        int t = r >> 6, c = r & 63;
#pragma unroll
        for (int j = 0; j < 4; ++j) {
          int m = tm + wm + mi * 16 + lg * 4 + j;
          int b = m >> 11, s = m & 2047;
          float v = acc[mi][ni][j] + bv;
          if (t == 0) v *= 0.18033688011112042f;
          size_t base = ((size_t)(b * NH + h) * 3 + t) * (size_t)(S_LEN * 64);
          size_t idx;
          if (t == 2) {
            int rs = s & 31;
            int rp = (((rs >> 2) & 3) << 3) | ((rs >> 4) << 2) | (rs & 3);
            idx = base + (size_t)c * S_LEN + (size_t)((s & ~31) | rp);
          } else {
            idx = base + (size_t)s * 64 + c;
          }
          outQ[idx] = (bf16_t)v;
        }
      }
  }
}

// ---------------- Flash attention: 64 q-rows/wave, T15 pipeline, MFMA denom ------
// (round-17 verbatim — passing at 4.88e-4)
__global__ __launch_bounds__(256, 2) void attn_fwd(const bf16_t* __restrict__ qkvb,
                                                   bf16_t* __restrict__ attnb) {
  __shared__ __attribute__((aligned(16))) bf16_t Ks[3][64 * 64];
  __shared__ __attribute__((aligned(16))) bf16_t Vs[3][64 * 64];  // V^T tile [d][key']
  const int tid = threadIdx.x, lane = tid & 63, wid = tid >> 6;
  const int l15 = lane & 15, lg = lane >> 4;
  int lin = blockIdx.x + (blockIdx.y << 3);   // grid (8,64): 512 blocks
  lin = (lin & 7) * 64 + (lin >> 3);          // XCD swizzle (bijective)
  const int qt = lin & 7;
  const int bh = lin >> 3;
  const int b = bh >> 4, h = bh & 15;
  const char* Qg = (const char*)qkvb + (size_t)bh * 3 * (S_LEN * 64) * 2;
  const char* Kg = Qg + (size_t)S_LEN * 64 * 2;
  const char* Vtg = Kg + (size_t)S_LEN * 64 * 2;
  const int q0 = tid * 16;

  bf16x8 qf[4][2];
#pragma unroll
  for (int mi = 0; mi < 4; ++mi) {
    const char* qr = Qg + (size_t)(qt * 256 + wid * 64 + mi * 16 + l15) * 128;
#pragma unroll
    for (int kb = 0; kb < 2; ++kb)
      qf[mi][kb] = *(const bf16x8*)(qr + kb * 64 + lg * 16);
  }

  auto stageK = [&](int t) {
#pragma unroll
    for (int i = 0; i < 2; ++i) {
      int q = q0 + i * 4096;
      int row = q >> 7;
      int scb = (q & 127) ^ ((row & 7) << 4);
      gld16((char*)Ks[t % 3] + (q & ~1023), Kg + (size_t)(t * 64 + row) * 128 + scb);
    }
  };
  auto stageV = [&](int t) {
#pragma unroll
    for (int i = 0; i < 2; ++i) {
      int q = q0 + i * 4096;
      int row = q >> 7;
      int scb = (q & 127) ^ ((row & 7) << 4);
      gld16((char*)Vs[t % 3] + (q & ~1023),
            Vtg + (size_t)row * (S_LEN * 2) + t * 128 + scb);
    }
  };

  f32x4 o[4][4] = {};
  f32x4 den[4] = {};
  bf16x8 pf[2][4];
  bf16x8 onesf;
#pragma unroll
  for (int j = 0; j < 8; ++j) onesf[j] = (bf16_t)1.0f;
  const int swk = (l15 & 7) << 4;

  auto QK = [&](const bf16_t* Kc, f32x4(&stv)[4][4]) {
#pragma unroll
    for (int nk = 0; nk < 4; ++nk) {
      const char* kr = (const char*)Kc + (nk * 16 + l15) * 128;
      bf16x8 kf0 = *(const bf16x8*)(kr + ((lg * 16) ^ swk));
      bf16x8 kf1 = *(const bf16x8*)(kr + ((64 + lg * 16) ^ swk));
#pragma unroll
      for (int mi = 0; mi < 4; ++mi) {
        f32x4 z = {};
        z = MFMA16(kf0, qf[mi][0], z);
        stv[mi][nk] = MFMA16(kf1, qf[mi][1], z);
      }
    }
  };
  auto SM = [&](f32x4(&stv)[4][4]) {
#pragma unroll
    for (int mi = 0; mi < 4; ++mi)
#pragma unroll
      for (int nk = 0; nk < 4; ++nk)
#pragma unroll
        for (int j = 0; j < 4; ++j)
          stv[mi][nk][j] = exp2_hw(stv[mi][nk][j]);
#pragma unroll
    for (int kp = 0; kp < 2; ++kp)
#pragma unroll
      for (int mi = 0; mi < 4; ++mi)
#pragma unroll
        for (int j = 0; j < 4; ++j) {
          pf[kp][mi][j] = (bf16_t)stv[mi][2 * kp][j];
          pf[kp][mi][4 + j] = (bf16_t)stv[mi][2 * kp + 1][j];
        }
  };
  auto PV = [&](const bf16_t* Vc) {
#pragma unroll
    for (int kp = 0; kp < 2; ++kp) {
#pragma unroll
      for (int ndv = 0; ndv < 4; ++ndv) {
        const char* vr = (const char*)Vc + (ndv * 16 + l15) * 128;
        bf16x8 vf = *(const bf16x8*)(vr + ((kp * 64 + 16 * lg) ^ swk));
#pragma unroll
        for (int mi = 0; mi < 4; ++mi)
          o[mi][ndv] = MFMA16(pf[kp][mi], vf, o[mi][ndv]);
      }
#pragma unroll
      for (int mi = 0; mi < 4; ++mi)
        den[mi] = MFMA16(pf[kp][mi], onesf, den[mi]);
    }
  };

  stageV(0); stageK(0); stageV(1); stageK(1); stageK(2);
  asm volatile("s_waitcnt vmcnt(6)" ::: "memory");
  __builtin_amdgcn_s_barrier();
  asm volatile("" ::: "memory");
  {
    f32x4 stv[4][4];
    __builtin_amdgcn_s_setprio(1);
    QK(Ks[0], stv);
    __builtin_amdgcn_s_setprio(0);
    SM(stv);
  }

  for (int kt = 0; kt < 30; ++kt) {
    asm volatile("s_waitcnt vmcnt(2)" ::: "memory");
    __builtin_amdgcn_s_barrier();
    asm volatile("" ::: "memory");
    stageV(kt + 2);
    if (kt + 3 < 32) stageK(kt + 3);
    f32x4 stv[4][4];
    __builtin_amdgcn_s_setprio(1);
    QK(Ks[(kt + 1) % 3], stv);
    PV(Vs[kt % 3]);
    __builtin_amdgcn_s_setprio(0);
    SM(stv);
  }
  asm volatile("s_waitcnt vmcnt(0)" ::: "memory");
  __builtin_amdgcn_s_barrier();
  asm volatile("" ::: "memory");
  {
    f32x4 stv[4][4];
    __builtin_amdgcn_s_setprio(1);
    QK(Ks[31 % 3], stv);
    PV(Vs[30 % 3]);
    __builtin_amdgcn_s_setprio(0);
    SM(stv);
  }
  PV(Vs[31 % 3]);

  float inv[4][4];
#pragma unroll
  for (int mi = 0; mi < 4; ++mi)
#pragma unroll
    for (int j = 0; j < 4; ++j)
      inv[mi][j] = 1.0f / den[mi][j];

#pragma unroll
  for (int mi = 0; mi < 4; ++mi)
#pragma unroll
    for (int j = 0; j < 4; ++j) {
      int srow = qt * 256 + wid * 64 + mi * 16 + lg * 4 + j;
      bf16_t* dst = attnb + ((size_t)b * S_LEN + srow) * D_EMB + h * 64;
#pragma unroll
      for (int ndv = 0; ndv < 4; ++ndv)
        dst[ndv * 16 + l15] = (bf16_t)(o[mi][ndv][j] * inv[mi][j]);
    }
}

// ---------------- launch ----------------
extern "C" void kernel_launch(void* const* d_in, const int* in_sizes, int n_in,
                              void* d_out, int out_size, void* d_ws, size_t ws_size,
                              hipStream_t stream) {
  const float* x = (const float*)d_in[0];
  const float* w_qkv = (const float*)d_in[1];
  const float* b_qkv = (const float*)d_in[2];
  const float* w_out = (const float*)d_in[3];
  const float* b_out = (const float*)d_in[4];
  float* out = (float*)d_out;

  bf16_t* xb = (bf16_t*)d_ws;            // 8388608 elems
  bf16_t* wqkvb = xb + 8388608;          // 3145728
  bf16_t* woutb = wqkvb + 3145728;       // 1048576
  bf16_t* qkvb = woutb + 1048576;        // 25165824 ([B][H][3][...])
  bf16_t* attnb = qkvb + 25165824;       // 8388608  (total ~92.3 MB)

  cvt_bf16<<<8192, 256, 0, stream>>>(x, xb, 2097152);
  cvt_bf16<<<3072, 256, 0, stream>>>(w_qkv, wqkvb, 786432);
  cvt_bf16<<<1024, 256, 0, stream>>>(w_out, woutb, 262144);

  gemm_qkv_8p<<<dim3(12, 32), 512, 0, stream>>>(xb, wqkvb, b_qkv, qkvb);
  attn_fwd<<<dim3(8, 64), 256, 0, stream>>>(qkvb, attnb);
  gemm_bt<0><<<dim3(8, 64), 256, 0, stream>>>(attnb, woutb, b_out, out, nullptr,
                                              8192, 1024, 1024);
}

// Round 20
// 181.835 us; speedup vs baseline: 1.0054x; 1.0054x over previous
//
#include <hip/hip_runtime.h>

typedef __bf16 bf16_t;
typedef __bf16 bf16x8 __attribute__((ext_vector_type(8)));
typedef __bf16 bf16x4 __attribute__((ext_vector_type(4)));
typedef float f32x4 __attribute__((ext_vector_type(4)));

#define S_LEN 2048
#define D_EMB 1024
#define NH 16

#define MFMA16(a, b, c) __builtin_amdgcn_mfma_f32_16x16x32_bf16((a), (b), (c), 0, 0, 0)
#define BARRIER()                        \
  asm volatile("" ::: "memory");         \
  __builtin_amdgcn_s_barrier();          \
  asm volatile("" ::: "memory")

__device__ __forceinline__ void gld16(void* lds, const void* g) {
  __builtin_amdgcn_global_load_lds(
      (__attribute__((address_space(1))) void*)(void*)(g),
      (__attribute__((address_space(3))) void*)(lds), 16, 0, 0);
}

__device__ __forceinline__ float exp2_hw(float x) {
  float r;
  asm("v_exp_f32 %0, %1" : "=v"(r) : "v"(x));
  return r;
}

// ---------------- fp32 -> bf16 convert ----------------
__global__ __launch_bounds__(256) void cvt_bf16(const float* __restrict__ in,
                                                bf16_t* __restrict__ out, int n4) {
  int i = blockIdx.x * 256 + threadIdx.x;
  if (i >= n4) return;
  float4 v = ((const float4*)in)[i];
  bf16x4 o;
  o[0] = (bf16_t)v.x; o[1] = (bf16_t)v.y; o[2] = (bf16_t)v.z; o[3] = (bf16_t)v.w;
  ((bf16x4*)out)[i] = o;
}

// ============ QKV GEMM: 4-phase 256^2 template (512 thr, 8 waves 2Mx4N) =========
// Round-19's 8-phase merged into 4 LONG phases/iter (32 MFMA each, kk0+kk1 fused):
// phase wall ~2x longer -> the fixed 2-3-phase prefetch slack now exceeds memory
// latency, so the vmcnt waits stop stalling. Barriers halve (8/iter).
// Geometry: BM=BN=256, BK=64, per-wave 128x64 (acc[8][4]). LDS 128KB (2 slots).
// Issue plan (iter t: tile e=2t in slot0 ph1-2, tile o=2t+1 in slot1 ph3-4):
//   ph1(e,mh0): stage A(o)x4      ph2(e,mh1): stage W(e+2)x2units
//   ph3(o,mh0): stage A(e+2)x4    ph4(o,mh1): stage W(o+2)x2units
// Global issue order = ...,W(m)4,A(m)4,W(m+1)4,A(m+1)4,... (8 loads per tile).
// Waits: ph1 vmcnt(4) (drains tile e, keeps W(o)4); ph3 vmcnt(4) (drains tile o,
// keeps W(e+2)4); t=7 ph3 vmcnt(0). WAR: every stage's target region had its last
// LDS-read consumed by an MFMA (lgkm-forced) before the intervening barrier.
__global__ __launch_bounds__(512, 2) void gemm_qkv_4p(
    const bf16_t* __restrict__ A, const bf16_t* __restrict__ W,
    const float* __restrict__ bias, bf16_t* __restrict__ outQ) {
  const int K = 1024;
  __shared__ __attribute__((aligned(16))) bf16_t As[2][256 * 64];
  __shared__ __attribute__((aligned(16))) bf16_t Ws[2][256 * 64];
  const int tid = threadIdx.x, lane = tid & 63, wid = tid >> 6;
  const int l15 = lane & 15, lg = lane >> 4;
  const int wm = wid >> 2, wn = wid & 3;
  int lin = blockIdx.x + 12 * blockIdx.y;  // 384 blocks (12 x 32)
  lin = (lin & 7) * 48 + (lin >> 3);       // XCD swizzle (bijective, 384%8==0)
  const int tm = (lin / 12) * 256, tn = (lin % 12) * 256;
  const int q0 = tid * 16;

  // A quarter (64 rows, 8KB): 1 gld16/thread
  auto stAq = [&](int kt, int quad, int slot) {
    int row = q0 >> 7;  // 0..63
    int scb = (q0 & 127) ^ ((row & 7) << 4);
    gld16((char*)As[slot] + quad * 8192 + (q0 & ~1023),
          (const char*)A + ((size_t)(tm + quad * 64 + row) * K + kt * 64) * 2 + scb);
  };
  // W half (128 rows, 16KB): 2 gld16/thread
  auto stWh = [&](int kt, int half, int slot) {
#pragma unroll
    for (int i = 0; i < 2; ++i) {
      int q = q0 + i * 8192;
      int row = q >> 7;  // 0..127
      int scb = (q & 127) ^ ((row & 7) << 4);
      gld16((char*)Ws[slot] + half * 16384 + (q & ~1023),
            (const char*)W + ((size_t)(tn + half * 128 + row) * K + kt * 64) * 2 + scb);
    }
  };
  auto rdA = [&](int slot, int mh, int kk, bf16x8(&af)[4]) {
#pragma unroll
    for (int m2 = 0; m2 < 4; ++m2) {
      int row = wm * 128 + mh * 64 + m2 * 16 + l15;
      af[m2] = *(const bf16x8*)((const char*)As[slot] + row * 128 +
                                ((kk * 64 + lg * 16) ^ ((row & 7) << 4)));
    }
  };
  auto rdB = [&](int slot, int kk, bf16x8(&bf)[4]) {
#pragma unroll
    for (int ni = 0; ni < 4; ++ni) {
      int col = wn * 64 + ni * 16 + l15;
      bf[ni] = *(const bf16x8*)((const char*)Ws[slot] + col * 128 +
                                ((kk * 64 + lg * 16) ^ ((col & 7) << 4)));
    }
  };

  f32x4 acc[8][4] = {};
  bf16x8 af0[4], af1[4], bf0[4], bf1[4];
  auto mm2 = [&](int mh) {  // 32 MFMA: both kk halves of one mh quadrant
    __builtin_amdgcn_s_setprio(1);
#pragma unroll
    for (int m2 = 0; m2 < 4; ++m2)
#pragma unroll
      for (int ni = 0; ni < 4; ++ni) {
        acc[mh * 4 + m2][ni] = MFMA16(af0[m2], bf0[ni], acc[mh * 4 + m2][ni]);
        acc[mh * 4 + m2][ni] = MFMA16(af1[m2], bf1[ni], acc[mh * 4 + m2][ni]);
      }
    __builtin_amdgcn_s_setprio(0);
  };

  // prologue: W(0), A(0) -> slot0; W(1) -> slot1  (12 loads/thread)
  stWh(0, 0, 0); stWh(0, 1, 0);
  stAq(0, 0, 0); stAq(0, 1, 0); stAq(0, 2, 0); stAq(0, 3, 0);
  stWh(1, 0, 1); stWh(1, 1, 1);

  for (int t = 0; t < 8; ++t) {
    const int e = 2 * t, o = 2 * t + 1;
    // ---- ph1: tile e (slot0), mh0, kk0+kk1
    asm volatile("s_waitcnt vmcnt(4)" ::: "memory");  // tile e landed; W(o) in flight
    BARRIER();
    stAq(o, 0, 1); stAq(o, 1, 1); stAq(o, 2, 1); stAq(o, 3, 1);
    rdA(0, 0, 0, af0); rdA(0, 0, 1, af1); rdB(0, 0, bf0); rdB(0, 1, bf1);
    BARRIER();
    mm2(0);
    // ---- ph2: tile e, mh1
    BARRIER();
    if (t < 7) { stWh(e + 2, 0, 0); stWh(e + 2, 1, 0); }
    rdA(0, 1, 0, af0); rdA(0, 1, 1, af1);
    BARRIER();
    mm2(1);
    // ---- ph3: tile o (slot1), mh0
    if (t < 7) {
      asm volatile("s_waitcnt vmcnt(4)" ::: "memory");  // tile o landed; W(e+2) in flight
    } else {
      asm volatile("s_waitcnt vmcnt(0)" ::: "memory");
    }
    BARRIER();
    if (t < 7) { stAq(e + 2, 0, 0); stAq(e + 2, 1, 0); stAq(e + 2, 2, 0); stAq(e + 2, 3, 0); }
    rdA(1, 0, 0, af0); rdA(1, 0, 1, af1); rdB(1, 0, bf0); rdB(1, 1, bf1);
    BARRIER();
    mm2(0);
    // ---- ph4: tile o, mh1
    BARRIER();
    if (t < 7) { stWh(o + 2, 0, 1); stWh(o + 2, 1, 1); }
    rdA(1, 1, 0, af0); rdA(1, 1, 1, af1);
    BARRIER();
    mm2(1);
  }

  // epilogue: qkv scatter (round-19 verbatim; V keys permuted within 32-blocks)
#pragma unroll
  for (int mi = 0; mi < 8; ++mi)
#pragma unroll
    for (int ni = 0; ni < 4; ++ni) {
      int e = tn + wn * 64 + ni * 16 + l15;
      float bv = bias[e];
      int h = e / 192;
      int r = e - h * 192;
      int tt = r >> 6, c = r & 63;
#pragma unroll
      for (int j = 0; j < 4; ++j) {
        int m = tm + wm * 128 + mi * 16 + lg * 4 + j;
        int b = m >> 11, s = m & 2047;
        float v = acc[mi][ni][j] + bv;
        if (tt == 0) v *= 0.18033688011112042f;  // (1/sqrt(64)) * log2(e)
        size_t base = ((size_t)(b * NH + h) * 3 + tt) * (size_t)(S_LEN * 64);
        size_t idx;
        if (tt == 2) {
          int rs = s & 31;
          int rp = (((rs >> 2) & 3) << 3) | ((rs >> 4) << 2) | (rs & 3);
          idx = base + (size_t)c * S_LEN + (size_t)((s & ~31) | rp);
        } else {
          idx = base + (size_t)s * 64 + c;
        }
        outQ[idx] = (bf16_t)v;
      }
    }
}

// ---------------- GEMM (round-18 dbuf version; used for out-proj only) ----------
template <int EPI>
__global__ __launch_bounds__(256) void gemm_bt(
    const bf16_t* __restrict__ A, const bf16_t* __restrict__ W,
    const float* __restrict__ bias, float* __restrict__ outF,
    bf16_t* __restrict__ outQ, int M, int N, int K) {
  __shared__ __attribute__((aligned(16))) bf16_t As[2][128 * 64];
  __shared__ __attribute__((aligned(16))) bf16_t Ws[2][128 * 64];
  const int tid = threadIdx.x;
  const int lane = tid & 63;
  const int wid = tid >> 6;
  const int l15 = lane & 15, lg = lane >> 4;
  int lin = blockIdx.x + gridDim.x * blockIdx.y;
  const int nwg = gridDim.x * gridDim.y;
  lin = (lin & 7) * (nwg >> 3) + (lin >> 3);  // XCD swizzle (bijective, nwg%8==0)
  const int tm = (lin / gridDim.x) * 128, tn = (lin % gridDim.x) * 128;
  const int wm = (wid >> 1) * 64, wn = (wid & 1) * 64;
  f32x4 acc[4][4] = {};
  const int q0 = tid * 16;

  auto stage = [&](int k0, int buf) {
#pragma unroll
    for (int i = 0; i < 4; ++i) {
      int q = q0 + i * 4096;
      int row = q >> 7;
      int scb = (q & 127) ^ ((row & 7) << 4);
      gld16((char*)As[buf] + (q & ~1023),
            (const char*)A + ((size_t)(tm + row) * K + k0) * 2 + scb);
      gld16((char*)Ws[buf] + (q & ~1023),
            (const char*)W + ((size_t)(tn + row) * K + k0) * 2 + scb);
    }
  };

  stage(0, 0);
  __syncthreads();

  const int nkt = K >> 6;
  for (int it = 0; it < nkt; ++it) {
    const int cur = it & 1;
    if (it + 1 < nkt) stage((it + 1) << 6, cur ^ 1);
#pragma unroll
    for (int kk = 0; kk < 2; ++kk) {
      const int cb = kk * 64 + lg * 16;
      bf16x8 af[4], bfr[4];
#pragma unroll
      for (int mi = 0; mi < 4; ++mi) {
        int row = wm + mi * 16 + l15;
        af[mi] = *(const bf16x8*)((const char*)As[cur] + row * 128 +
                                  (cb ^ ((row & 7) << 4)));
      }
#pragma unroll
      for (int ni = 0; ni < 4; ++ni) {
        int row = wn + ni * 16 + l15;
        bfr[ni] = *(const bf16x8*)((const char*)Ws[cur] + row * 128 +
                                   (cb ^ ((row & 7) << 4)));
      }
#pragma unroll
      for (int mi = 0; mi < 4; ++mi)
#pragma unroll
        for (int ni = 0; ni < 4; ++ni)
          acc[mi][ni] = MFMA16(af[mi], bfr[ni], acc[mi][ni]);
    }
    if (it + 1 < nkt) __syncthreads();
  }

  if (EPI == 0) {
#pragma unroll
    for (int mi = 0; mi < 4; ++mi)
#pragma unroll
      for (int ni = 0; ni < 4; ++ni) {
        int colg = tn + wn + ni * 16 + l15;
        float bv = bias[colg];
#pragma unroll
        for (int j = 0; j < 4; ++j) {
          int rowg = tm + wm + mi * 16 + lg * 4 + j;
          outF[(size_t)rowg * N + colg] = acc[mi][ni][j] + bv;
        }
      }
  } else {
#pragma unroll
    for (int mi = 0; mi < 4; ++mi)
#pragma unroll
      for (int ni = 0; ni < 4; ++ni) {
        int e = tn + wn + ni * 16 + l15;
        float bv = bias[e];
        int h = e / 192;
        int r = e - h * 192;
        int t = r >> 6, c = r & 63;
#pragma unroll
        for (int j = 0; j < 4; ++j) {
          int m = tm + wm + mi * 16 + lg * 4 + j;
          int b = m >> 11, s = m & 2047;
          float v = acc[mi][ni][j] + bv;
          if (t == 0) v *= 0.18033688011112042f;
          size_t base = ((size_t)(b * NH + h) * 3 + t) * (size_t)(S_LEN * 64);
          size_t idx;
          if (t == 2) {
            int rs = s & 31;
            int rp = (((rs >> 2) & 3) << 3) | ((rs >> 4) << 2) | (rs & 3);
            idx = base + (size_t)c * S_LEN + (size_t)((s & ~31) | rp);
          } else {
            idx = base + (size_t)s * 64 + c;
          }
          outQ[idx] = (bf16_t)v;
        }
      }
  }
}

// ---------------- Flash attention: 64 q-rows/wave, T15 pipeline, MFMA denom ------
// (round-17 verbatim — passing at 4.88e-4)
__global__ __launch_bounds__(256, 2) void attn_fwd(const bf16_t* __restrict__ qkvb,
                                                   bf16_t* __restrict__ attnb) {
  __shared__ __attribute__((aligned(16))) bf16_t Ks[3][64 * 64];
  __shared__ __attribute__((aligned(16))) bf16_t Vs[3][64 * 64];  // V^T tile [d][key']
  const int tid = threadIdx.x, lane = tid & 63, wid = tid >> 6;
  const int l15 = lane & 15, lg = lane >> 4;
  int lin = blockIdx.x + (blockIdx.y << 3);   // grid (8,64): 512 blocks
  lin = (lin & 7) * 64 + (lin >> 3);          // XCD swizzle (bijective)
  const int qt = lin & 7;
  const int bh = lin >> 3;
  const int b = bh >> 4, h = bh & 15;
  const char* Qg = (const char*)qkvb + (size_t)bh * 3 * (S_LEN * 64) * 2;
  const char* Kg = Qg + (size_t)S_LEN * 64 * 2;
  const char* Vtg = Kg + (size_t)S_LEN * 64 * 2;
  const int q0 = tid * 16;

  bf16x8 qf[4][2];
#pragma unroll
  for (int mi = 0; mi < 4; ++mi) {
    const char* qr = Qg + (size_t)(qt * 256 + wid * 64 + mi * 16 + l15) * 128;
#pragma unroll
    for (int kb = 0; kb < 2; ++kb)
      qf[mi][kb] = *(const bf16x8*)(qr + kb * 64 + lg * 16);
  }

  auto stageK = [&](int t) {
#pragma unroll
    for (int i = 0; i < 2; ++i) {
      int q = q0 + i * 4096;
      int row = q >> 7;
      int scb = (q & 127) ^ ((row & 7) << 4);
      gld16((char*)Ks[t % 3] + (q & ~1023), Kg + (size_t)(t * 64 + row) * 128 + scb);
    }
  };
  auto stageV = [&](int t) {
#pragma unroll
    for (int i = 0; i < 2; ++i) {
      int q = q0 + i * 4096;
      int row = q >> 7;
      int scb = (q & 127) ^ ((row & 7) << 4);
      gld16((char*)Vs[t % 3] + (q & ~1023),
            Vtg + (size_t)row * (S_LEN * 2) + t * 128 + scb);
    }
  };

  f32x4 o[4][4] = {};
  f32x4 den[4] = {};
  bf16x8 pf[2][4];
  bf16x8 onesf;
#pragma unroll
  for (int j = 0; j < 8; ++j) onesf[j] = (bf16_t)1.0f;
  const int swk = (l15 & 7) << 4;

  auto QK = [&](const bf16_t* Kc, f32x4(&stv)[4][4]) {
#pragma unroll
    for (int nk = 0; nk < 4; ++nk) {
      const char* kr = (const char*)Kc + (nk * 16 + l15) * 128;
      bf16x8 kf0 = *(const bf16x8*)(kr + ((lg * 16) ^ swk));
      bf16x8 kf1 = *(const bf16x8*)(kr + ((64 + lg * 16) ^ swk));
#pragma unroll
      for (int mi = 0; mi < 4; ++mi) {
        f32x4 z = {};
        z = MFMA16(kf0, qf[mi][0], z);
        stv[mi][nk] = MFMA16(kf1, qf[mi][1], z);
      }
    }
  };
  auto SM = [&](f32x4(&stv)[4][4]) {
#pragma unroll
    for (int mi = 0; mi < 4; ++mi)
#pragma unroll
      for (int nk = 0; nk < 4; ++nk)
#pragma unroll
        for (int j = 0; j < 4; ++j)
          stv[mi][nk][j] = exp2_hw(stv[mi][nk][j]);
#pragma unroll
    for (int kp = 0; kp < 2; ++kp)
#pragma unroll
      for (int mi = 0; mi < 4; ++mi)
#pragma unroll
        for (int j = 0; j < 4; ++j) {
          pf[kp][mi][j] = (bf16_t)stv[mi][2 * kp][j];
          pf[kp][mi][4 + j] = (bf16_t)stv[mi][2 * kp + 1][j];
        }
  };
  auto PV = [&](const bf16_t* Vc) {
#pragma unroll
    for (int kp = 0; kp < 2; ++kp) {
#pragma unroll
      for (int ndv = 0; ndv < 4; ++ndv) {
        const char* vr = (const char*)Vc + (ndv * 16 + l15) * 128;
        bf16x8 vf = *(const bf16x8*)(vr + ((kp * 64 + 16 * lg) ^ swk));
#pragma unroll
        for (int mi = 0; mi < 4; ++mi)
          o[mi][ndv] = MFMA16(pf[kp][mi], vf, o[mi][ndv]);
      }
#pragma unroll
      for (int mi = 0; mi < 4; ++mi)
        den[mi] = MFMA16(pf[kp][mi], onesf, den[mi]);
    }
  };

  stageV(0); stageK(0); stageV(1); stageK(1); stageK(2);
  asm volatile("s_waitcnt vmcnt(6)" ::: "memory");
  __builtin_amdgcn_s_barrier();
  asm volatile("" ::: "memory");
  {
    f32x4 stv[4][4];
    __builtin_amdgcn_s_setprio(1);
    QK(Ks[0], stv);
    __builtin_amdgcn_s_setprio(0);
    SM(stv);
  }

  for (int kt = 0; kt < 30; ++kt) {
    asm volatile("s_waitcnt vmcnt(2)" ::: "memory");
    __builtin_amdgcn_s_barrier();
    asm volatile("" ::: "memory");
    stageV(kt + 2);
    if (kt + 3 < 32) stageK(kt + 3);
    f32x4 stv[4][4];
    __builtin_amdgcn_s_setprio(1);
    QK(Ks[(kt + 1) % 3], stv);
    PV(Vs[kt % 3]);
    __builtin_amdgcn_s_setprio(0);
    SM(stv);
  }
  asm volatile("s_waitcnt vmcnt(0)" ::: "memory");
  __builtin_amdgcn_s_barrier();
  asm volatile("" ::: "memory");
  {
    f32x4 stv[4][4];
    __builtin_amdgcn_s_setprio(1);
    QK(Ks[31 % 3], stv);
    PV(Vs[30 % 3]);
    __builtin_amdgcn_s_setprio(0);
    SM(stv);
  }
  PV(Vs[31 % 3]);

  float inv[4][4];
#pragma unroll
  for (int mi = 0; mi < 4; ++mi)
#pragma unroll
    for (int j = 0; j < 4; ++j)
      inv[mi][j] = 1.0f / den[mi][j];

#pragma unroll
  for (int mi = 0; mi < 4; ++mi)
#pragma unroll
    for (int j = 0; j < 4; ++j) {
      int srow = qt * 256 + wid * 64 + mi * 16 + lg * 4 + j;
      bf16_t* dst = attnb + ((size_t)b * S_LEN + srow) * D_EMB + h * 64;
#pragma unroll
      for (int ndv = 0; ndv < 4; ++ndv)
        dst[ndv * 16 + l15] = (bf16_t)(o[mi][ndv][j] * inv[mi][j]);
    }
}

// ---------------- launch ----------------
extern "C" void kernel_launch(void* const* d_in, const int* in_sizes, int n_in,
                              void* d_out, int out_size, void* d_ws, size_t ws_size,
                              hipStream_t stream) {
  const float* x = (const float*)d_in[0];
  const float* w_qkv = (const float*)d_in[1];
  const float* b_qkv = (const float*)d_in[2];
  const float* w_out = (const float*)d_in[3];
  const float* b_out = (const float*)d_in[4];
  float* out = (float*)d_out;

  bf16_t* xb = (bf16_t*)d_ws;            // 8388608 elems
  bf16_t* wqkvb = xb + 8388608;          // 3145728
  bf16_t* woutb = wqkvb + 3145728;       // 1048576
  bf16_t* qkvb = woutb + 1048576;        // 25165824 ([B][H][3][...])
  bf16_t* attnb = qkvb + 25165824;       // 8388608  (total ~92.3 MB)

  cvt_bf16<<<8192, 256, 0, stream>>>(x, xb, 2097152);
  cvt_bf16<<<3072, 256, 0, stream>>>(w_qkv, wqkvb, 786432);
  cvt_bf16<<<1024, 256, 0, stream>>>(w_out, woutb, 262144);

  gemm_qkv_4p<<<dim3(12, 32), 512, 0, stream>>>(xb, wqkvb, b_qkv, qkvb);
  attn_fwd<<<dim3(8, 64), 256, 0, stream>>>(qkvb, attnb);
  gemm_bt<0><<<dim3(8, 64), 256, 0, stream>>>(attnb, woutb, b_out, out, nullptr,
                                              8192, 1024, 1024);
}

// Round 21
// 178.609 us; speedup vs baseline: 1.0236x; 1.0181x over previous
//
#include <hip/hip_runtime.h>

typedef __bf16 bf16_t;
typedef __bf16 bf16x8 __attribute__((ext_vector_type(8)));
typedef __bf16 bf16x4 __attribute__((ext_vector_type(4)));
typedef float f32x4 __attribute__((ext_vector_type(4)));

#define S_LEN 2048
#define D_EMB 1024
#define NH 16

#define MFMA16(a, b, c) __builtin_amdgcn_mfma_f32_16x16x32_bf16((a), (b), (c), 0, 0, 0)
#define BARRIER()                        \
  asm volatile("" ::: "memory");         \
  __builtin_amdgcn_s_barrier();          \
  asm volatile("" ::: "memory")

__device__ __forceinline__ void gld16(void* lds, const void* g) {
  __builtin_amdgcn_global_load_lds(
      (__attribute__((address_space(1))) void*)(void*)(g),
      (__attribute__((address_space(3))) void*)(lds), 16, 0, 0);
}

__device__ __forceinline__ float exp2_hw(float x) {
  float r;
  asm("v_exp_f32 %0, %1" : "=v"(r) : "v"(x));
  return r;
}

// ---------------- fp32 -> bf16 convert ----------------
__global__ __launch_bounds__(256) void cvt_bf16(const float* __restrict__ in,
                                                bf16_t* __restrict__ out, int n4) {
  int i = blockIdx.x * 256 + threadIdx.x;
  if (i >= n4) return;
  float4 v = ((const float4*)in)[i];
  bf16x4 o;
  o[0] = (bf16_t)v.x; o[1] = (bf16_t)v.y; o[2] = (bf16_t)v.z; o[3] = (bf16_t)v.w;
  ((bf16x4*)out)[i] = o;
}

// ============ QKV GEMM: 4-phase 256^2, ONE barrier per phase (round 21) =========
// Round-20 structure with the 4 correctness-dead mid-phase barriers removed:
// the pre-MFMA barrier only ordered reads feeding MY OWN registers (already
// ordered by the MFMA's lgkm waits); removing it halves barrier convoy cost and
// lets the compiler interleave ds_reads with MFMAs within the phase (m201's key
// property). Minimal barrier set = one per phase top: every stage targets a
// region whose last reads were register-consumed (MFMA-forced lgkm drain) before
// that barrier, and each stage sits right after a BARRIER() compiler fence.
// Waits unchanged: ph1 vmcnt(4); ph3 vmcnt(4) (t=7: vmcnt(0)).
__global__ __launch_bounds__(512, 2) void gemm_qkv_4p(
    const bf16_t* __restrict__ A, const bf16_t* __restrict__ W,
    const float* __restrict__ bias, bf16_t* __restrict__ outQ) {
  const int K = 1024;
  __shared__ __attribute__((aligned(16))) bf16_t As[2][256 * 64];
  __shared__ __attribute__((aligned(16))) bf16_t Ws[2][256 * 64];
  const int tid = threadIdx.x, lane = tid & 63, wid = tid >> 6;
  const int l15 = lane & 15, lg = lane >> 4;
  const int wm = wid >> 2, wn = wid & 3;
  int lin = blockIdx.x + 12 * blockIdx.y;  // 384 blocks (12 x 32)
  lin = (lin & 7) * 48 + (lin >> 3);       // XCD swizzle (bijective, 384%8==0)
  const int tm = (lin / 12) * 256, tn = (lin % 12) * 256;
  const int q0 = tid * 16;

  // A quarter (64 rows, 8KB): 1 gld16/thread
  auto stAq = [&](int kt, int quad, int slot) {
    int row = q0 >> 7;  // 0..63
    int scb = (q0 & 127) ^ ((row & 7) << 4);
    gld16((char*)As[slot] + quad * 8192 + (q0 & ~1023),
          (const char*)A + ((size_t)(tm + quad * 64 + row) * K + kt * 64) * 2 + scb);
  };
  // W half (128 rows, 16KB): 2 gld16/thread
  auto stWh = [&](int kt, int half, int slot) {
#pragma unroll
    for (int i = 0; i < 2; ++i) {
      int q = q0 + i * 8192;
      int row = q >> 7;  // 0..127
      int scb = (q & 127) ^ ((row & 7) << 4);
      gld16((char*)Ws[slot] + half * 16384 + (q & ~1023),
            (const char*)W + ((size_t)(tn + half * 128 + row) * K + kt * 64) * 2 + scb);
    }
  };
  auto rdA = [&](int slot, int mh, int kk, bf16x8(&af)[4]) {
#pragma unroll
    for (int m2 = 0; m2 < 4; ++m2) {
      int row = wm * 128 + mh * 64 + m2 * 16 + l15;
      af[m2] = *(const bf16x8*)((const char*)As[slot] + row * 128 +
                                ((kk * 64 + lg * 16) ^ ((row & 7) << 4)));
    }
  };
  auto rdB = [&](int slot, int kk, bf16x8(&bf)[4]) {
#pragma unroll
    for (int ni = 0; ni < 4; ++ni) {
      int col = wn * 64 + ni * 16 + l15;
      bf[ni] = *(const bf16x8*)((const char*)Ws[slot] + col * 128 +
                                ((kk * 64 + lg * 16) ^ ((col & 7) << 4)));
    }
  };

  f32x4 acc[8][4] = {};
  bf16x8 af0[4], af1[4], bf0[4], bf1[4];
  auto mm2 = [&](int mh) {  // 32 MFMA: both kk halves of one mh quadrant
    __builtin_amdgcn_s_setprio(1);
#pragma unroll
    for (int m2 = 0; m2 < 4; ++m2)
#pragma unroll
      for (int ni = 0; ni < 4; ++ni) {
        acc[mh * 4 + m2][ni] = MFMA16(af0[m2], bf0[ni], acc[mh * 4 + m2][ni]);
        acc[mh * 4 + m2][ni] = MFMA16(af1[m2], bf1[ni], acc[mh * 4 + m2][ni]);
      }
    __builtin_amdgcn_s_setprio(0);
  };

  // prologue: W(0), A(0) -> slot0; W(1) -> slot1  (12 loads/thread)
  stWh(0, 0, 0); stWh(0, 1, 0);
  stAq(0, 0, 0); stAq(0, 1, 0); stAq(0, 2, 0); stAq(0, 3, 0);
  stWh(1, 0, 1); stWh(1, 1, 1);

  for (int t = 0; t < 8; ++t) {
    const int e = 2 * t, o = 2 * t + 1;
    // ---- ph1: tile e (slot0), mh0, kk0+kk1
    asm volatile("s_waitcnt vmcnt(4)" ::: "memory");  // tile e landed; W(o) in flight
    BARRIER();
    stAq(o, 0, 1); stAq(o, 1, 1); stAq(o, 2, 1); stAq(o, 3, 1);
    rdA(0, 0, 0, af0); rdA(0, 0, 1, af1); rdB(0, 0, bf0); rdB(0, 1, bf1);
    mm2(0);
    // ---- ph2: tile e, mh1 (bf0/bf1 reused from registers)
    BARRIER();
    if (t < 7) { stWh(e + 2, 0, 0); stWh(e + 2, 1, 0); }
    rdA(0, 1, 0, af0); rdA(0, 1, 1, af1);
    mm2(1);
    // ---- ph3: tile o (slot1), mh0
    if (t < 7) {
      asm volatile("s_waitcnt vmcnt(4)" ::: "memory");  // tile o landed; W(e+2) in flight
    } else {
      asm volatile("s_waitcnt vmcnt(0)" ::: "memory");
    }
    BARRIER();
    if (t < 7) { stAq(e + 2, 0, 0); stAq(e + 2, 1, 0); stAq(e + 2, 2, 0); stAq(e + 2, 3, 0); }
    rdA(1, 0, 0, af0); rdA(1, 0, 1, af1); rdB(1, 0, bf0); rdB(1, 1, bf1);
    mm2(0);
    // ---- ph4: tile o, mh1
    BARRIER();
    if (t < 7) { stWh(o + 2, 0, 1); stWh(o + 2, 1, 1); }
    rdA(1, 1, 0, af0); rdA(1, 1, 1, af1);
    mm2(1);
  }

  // epilogue: qkv scatter (round-19 verbatim; V keys permuted within 32-blocks)
#pragma unroll
  for (int mi = 0; mi < 8; ++mi)
#pragma unroll
    for (int ni = 0; ni < 4; ++ni) {
      int e = tn + wn * 64 + ni * 16 + l15;
      float bv = bias[e];
      int h = e / 192;
      int r = e - h * 192;
      int tt = r >> 6, c = r & 63;
#pragma unroll
      for (int j = 0; j < 4; ++j) {
        int m = tm + wm * 128 + mi * 16 + lg * 4 + j;
        int b = m >> 11, s = m & 2047;
        float v = acc[mi][ni][j] + bv;
        if (tt == 0) v *= 0.18033688011112042f;  // (1/sqrt(64)) * log2(e)
        size_t base = ((size_t)(b * NH + h) * 3 + tt) * (size_t)(S_LEN * 64);
        size_t idx;
        if (tt == 2) {
          int rs = s & 31;
          int rp = (((rs >> 2) & 3) << 3) | ((rs >> 4) << 2) | (rs & 3);
          idx = base + (size_t)c * S_LEN + (size_t)((s & ~31) | rp);
        } else {
          idx = base + (size_t)s * 64 + c;
        }
        outQ[idx] = (bf16_t)v;
      }
    }
}

// ---------------- GEMM (round-18 dbuf version; used for out-proj only) ----------
template <int EPI>
__global__ __launch_bounds__(256) void gemm_bt(
    const bf16_t* __restrict__ A, const bf16_t* __restrict__ W,
    const float* __restrict__ bias, float* __restrict__ outF,
    bf16_t* __restrict__ outQ, int M, int N, int K) {
  __shared__ __attribute__((aligned(16))) bf16_t As[2][128 * 64];
  __shared__ __attribute__((aligned(16))) bf16_t Ws[2][128 * 64];
  const int tid = threadIdx.x;
  const int lane = tid & 63;
  const int wid = tid >> 6;
  const int l15 = lane & 15, lg = lane >> 4;
  int lin = blockIdx.x + gridDim.x * blockIdx.y;
  const int nwg = gridDim.x * gridDim.y;
  lin = (lin & 7) * (nwg >> 3) + (lin >> 3);  // XCD swizzle (bijective, nwg%8==0)
  const int tm = (lin / gridDim.x) * 128, tn = (lin % gridDim.x) * 128;
  const int wm = (wid >> 1) * 64, wn = (wid & 1) * 64;
  f32x4 acc[4][4] = {};
  const int q0 = tid * 16;

  auto stage = [&](int k0, int buf) {
#pragma unroll
    for (int i = 0; i < 4; ++i) {
      int q = q0 + i * 4096;
      int row = q >> 7;
      int scb = (q & 127) ^ ((row & 7) << 4);
      gld16((char*)As[buf] + (q & ~1023),
            (const char*)A + ((size_t)(tm + row) * K + k0) * 2 + scb);
      gld16((char*)Ws[buf] + (q & ~1023),
            (const char*)W + ((size_t)(tn + row) * K + k0) * 2 + scb);
    }
  };

  stage(0, 0);
  __syncthreads();

  const int nkt = K >> 6;
  for (int it = 0; it < nkt; ++it) {
    const int cur = it & 1;
    if (it + 1 < nkt) stage((it + 1) << 6, cur ^ 1);
#pragma unroll
    for (int kk = 0; kk < 2; ++kk) {
      const int cb = kk * 64 + lg * 16;
      bf16x8 af[4], bfr[4];
#pragma unroll
      for (int mi = 0; mi < 4; ++mi) {
        int row = wm + mi * 16 + l15;
        af[mi] = *(const bf16x8*)((const char*)As[cur] + row * 128 +
                                  (cb ^ ((row & 7) << 4)));
      }
#pragma unroll
      for (int ni = 0; ni < 4; ++ni) {
        int row = wn + ni * 16 + l15;
        bfr[ni] = *(const bf16x8*)((const char*)Ws[cur] + row * 128 +
                                   (cb ^ ((row & 7) << 4)));
      }
#pragma unroll
      for (int mi = 0; mi < 4; ++mi)
#pragma unroll
        for (int ni = 0; ni < 4; ++ni)
          acc[mi][ni] = MFMA16(af[mi], bfr[ni], acc[mi][ni]);
    }
    if (it + 1 < nkt) __syncthreads();
  }

  if (EPI == 0) {
#pragma unroll
    for (int mi = 0; mi < 4; ++mi)
#pragma unroll
      for (int ni = 0; ni < 4; ++ni) {
        int colg = tn + wn + ni * 16 + l15;
        float bv = bias[colg];
#pragma unroll
        for (int j = 0; j < 4; ++j) {
          int rowg = tm + wm + mi * 16 + lg * 4 + j;
          outF[(size_t)rowg * N + colg] = acc[mi][ni][j] + bv;
        }
      }
  } else {
#pragma unroll
    for (int mi = 0; mi < 4; ++mi)
#pragma unroll
      for (int ni = 0; ni < 4; ++ni) {
        int e = tn + wn + ni * 16 + l15;
        float bv = bias[e];
        int h = e / 192;
        int r = e - h * 192;
        int t = r >> 6, c = r & 63;
#pragma unroll
        for (int j = 0; j < 4; ++j) {
          int m = tm + wm + mi * 16 + lg * 4 + j;
          int b = m >> 11, s = m & 2047;
          float v = acc[mi][ni][j] + bv;
          if (t == 0) v *= 0.18033688011112042f;
          size_t base = ((size_t)(b * NH + h) * 3 + t) * (size_t)(S_LEN * 64);
          size_t idx;
          if (t == 2) {
            int rs = s & 31;
            int rp = (((rs >> 2) & 3) << 3) | ((rs >> 4) << 2) | (rs & 3);
            idx = base + (size_t)c * S_LEN + (size_t)((s & ~31) | rp);
          } else {
            idx = base + (size_t)s * 64 + c;
          }
          outQ[idx] = (bf16_t)v;
        }
      }
  }
}

// ---------------- Flash attention: 64 q-rows/wave, T15 pipeline, MFMA denom ------
// (round-17 verbatim — passing at 4.88e-4)
__global__ __launch_bounds__(256, 2) void attn_fwd(const bf16_t* __restrict__ qkvb,
                                                   bf16_t* __restrict__ attnb) {
  __shared__ __attribute__((aligned(16))) bf16_t Ks[3][64 * 64];
  __shared__ __attribute__((aligned(16))) bf16_t Vs[3][64 * 64];  // V^T tile [d][key']
  const int tid = threadIdx.x, lane = tid & 63, wid = tid >> 6;
  const int l15 = lane & 15, lg = lane >> 4;
  int lin = blockIdx.x + (blockIdx.y << 3);   // grid (8,64): 512 blocks
  lin = (lin & 7) * 64 + (lin >> 3);          // XCD swizzle (bijective)
  const int qt = lin & 7;
  const int bh = lin >> 3;
  const int b = bh >> 4, h = bh & 15;
  const char* Qg = (const char*)qkvb + (size_t)bh * 3 * (S_LEN * 64) * 2;
  const char* Kg = Qg + (size_t)S_LEN * 64 * 2;
  const char* Vtg = Kg + (size_t)S_LEN * 64 * 2;
  const int q0 = tid * 16;

  bf16x8 qf[4][2];
#pragma unroll
  for (int mi = 0; mi < 4; ++mi) {
    const char* qr = Qg + (size_t)(qt * 256 + wid * 64 + mi * 16 + l15) * 128;
#pragma unroll
    for (int kb = 0; kb < 2; ++kb)
      qf[mi][kb] = *(const bf16x8*)(qr + kb * 64 + lg * 16);
  }

  auto stageK = [&](int t) {
#pragma unroll
    for (int i = 0; i < 2; ++i) {
      int q = q0 + i * 4096;
      int row = q >> 7;
      int scb = (q & 127) ^ ((row & 7) << 4);
      gld16((char*)Ks[t % 3] + (q & ~1023), Kg + (size_t)(t * 64 + row) * 128 + scb);
    }
  };
  auto stageV = [&](int t) {
#pragma unroll
    for (int i = 0; i < 2; ++i) {
      int q = q0 + i * 4096;
      int row = q >> 7;
      int scb = (q & 127) ^ ((row & 7) << 4);
      gld16((char*)Vs[t % 3] + (q & ~1023),
            Vtg + (size_t)row * (S_LEN * 2) + t * 128 + scb);
    }
  };

  f32x4 o[4][4] = {};
  f32x4 den[4] = {};
  bf16x8 pf[2][4];
  bf16x8 onesf;
#pragma unroll
  for (int j = 0; j < 8; ++j) onesf[j] = (bf16_t)1.0f;
  const int swk = (l15 & 7) << 4;

  auto QK = [&](const bf16_t* Kc, f32x4(&stv)[4][4]) {
#pragma unroll
    for (int nk = 0; nk < 4; ++nk) {
      const char* kr = (const char*)Kc + (nk * 16 + l15) * 128;
      bf16x8 kf0 = *(const bf16x8*)(kr + ((lg * 16) ^ swk));
      bf16x8 kf1 = *(const bf16x8*)(kr + ((64 + lg * 16) ^ swk));
#pragma unroll
      for (int mi = 0; mi < 4; ++mi) {
        f32x4 z = {};
        z = MFMA16(kf0, qf[mi][0], z);
        stv[mi][nk] = MFMA16(kf1, qf[mi][1], z);
      }
    }
  };
  auto SM = [&](f32x4(&stv)[4][4]) {
#pragma unroll
    for (int mi = 0; mi < 4; ++mi)
#pragma unroll
      for (int nk = 0; nk < 4; ++nk)
#pragma unroll
        for (int j = 0; j < 4; ++j)
          stv[mi][nk][j] = exp2_hw(stv[mi][nk][j]);
#pragma unroll
    for (int kp = 0; kp < 2; ++kp)
#pragma unroll
      for (int mi = 0; mi < 4; ++mi)
#pragma unroll
        for (int j = 0; j < 4; ++j) {
          pf[kp][mi][j] = (bf16_t)stv[mi][2 * kp][j];
          pf[kp][mi][4 + j] = (bf16_t)stv[mi][2 * kp + 1][j];
        }
  };
  auto PV = [&](const bf16_t* Vc) {
#pragma unroll
    for (int kp = 0; kp < 2; ++kp) {
#pragma unroll
      for (int ndv = 0; ndv < 4; ++ndv) {
        const char* vr = (const char*)Vc + (ndv * 16 + l15) * 128;
        bf16x8 vf = *(const bf16x8*)(vr + ((kp * 64 + 16 * lg) ^ swk));
#pragma unroll
        for (int mi = 0; mi < 4; ++mi)
          o[mi][ndv] = MFMA16(pf[kp][mi], vf, o[mi][ndv]);
      }
#pragma unroll
      for (int mi = 0; mi < 4; ++mi)
        den[mi] = MFMA16(pf[kp][mi], onesf, den[mi]);
    }
  };

  stageV(0); stageK(0); stageV(1); stageK(1); stageK(2);
  asm volatile("s_waitcnt vmcnt(6)" ::: "memory");
  __builtin_amdgcn_s_barrier();
  asm volatile("" ::: "memory");
  {
    f32x4 stv[4][4];
    __builtin_amdgcn_s_setprio(1);
    QK(Ks[0], stv);
    __builtin_amdgcn_s_setprio(0);
    SM(stv);
  }

  for (int kt = 0; kt < 30; ++kt) {
    asm volatile("s_waitcnt vmcnt(2)" ::: "memory");
    __builtin_amdgcn_s_barrier();
    asm volatile("" ::: "memory");
    stageV(kt + 2);
    if (kt + 3 < 32) stageK(kt + 3);
    f32x4 stv[4][4];
    __builtin_amdgcn_s_setprio(1);
    QK(Ks[(kt + 1) % 3], stv);
    PV(Vs[kt % 3]);
    __builtin_amdgcn_s_setprio(0);
    SM(stv);
  }
  asm volatile("s_waitcnt vmcnt(0)" ::: "memory");
  __builtin_amdgcn_s_barrier();
  asm volatile("" ::: "memory");
  {
    f32x4 stv[4][4];
    __builtin_amdgcn_s_setprio(1);
    QK(Ks[31 % 3], stv);
    PV(Vs[30 % 3]);
    __builtin_amdgcn_s_setprio(0);
    SM(stv);
  }
  PV(Vs[31 % 3]);

  float inv[4][4];
#pragma unroll
  for (int mi = 0; mi < 4; ++mi)
#pragma unroll
    for (int j = 0; j < 4; ++j)
      inv[mi][j] = 1.0f / den[mi][j];

#pragma unroll
  for (int mi = 0; mi < 4; ++mi)
#pragma unroll
    for (int j = 0; j < 4; ++j) {
      int srow = qt * 256 + wid * 64 + mi * 16 + lg * 4 + j;
      bf16_t* dst = attnb + ((size_t)b * S_LEN + srow) * D_EMB + h * 64;
#pragma unroll
      for (int ndv = 0; ndv < 4; ++ndv)
        dst[ndv * 16 + l15] = (bf16_t)(o[mi][ndv][j] * inv[mi][j]);
    }
}

// ---------------- launch ----------------
extern "C" void kernel_launch(void* const* d_in, const int* in_sizes, int n_in,
                              void* d_out, int out_size, void* d_ws, size_t ws_size,
                              hipStream_t stream) {
  const float* x = (const float*)d_in[0];
  const float* w_qkv = (const float*)d_in[1];
  const float* b_qkv = (const float*)d_in[2];
  const float* w_out = (const float*)d_in[3];
  const float* b_out = (const float*)d_in[4];
  float* out = (float*)d_out;

  bf16_t* xb = (bf16_t*)d_ws;            // 8388608 elems
  bf16_t* wqkvb = xb + 8388608;          // 3145728
  bf16_t* woutb = wqkvb + 3145728;       // 1048576
  bf16_t* qkvb = woutb + 1048576;        // 25165824 ([B][H][3][...])
  bf16_t* attnb = qkvb + 25165824;       // 8388608  (total ~92.3 MB)

  cvt_bf16<<<8192, 256, 0, stream>>>(x, xb, 2097152);
  cvt_bf16<<<3072, 256, 0, stream>>>(w_qkv, wqkvb, 786432);
  cvt_bf16<<<1024, 256, 0, stream>>>(w_out, woutb, 262144);

  gemm_qkv_4p<<<dim3(12, 32), 512, 0, stream>>>(xb, wqkvb, b_qkv, qkvb);
  attn_fwd<<<dim3(8, 64), 256, 0, stream>>>(qkvb, attnb);
  gemm_bt<0><<<dim3(8, 64), 256, 0, stream>>>(attnb, woutb, b_out, out, nullptr,
                                              8192, 1024, 1024);
}

// Round 22
// 174.933 us; speedup vs baseline: 1.0451x; 1.0210x over previous
//
#include <hip/hip_runtime.h>

typedef __bf16 bf16_t;
typedef __bf16 bf16x8 __attribute__((ext_vector_type(8)));
typedef __bf16 bf16x4 __attribute__((ext_vector_type(4)));
typedef float f32x4 __attribute__((ext_vector_type(4)));

#define S_LEN 2048
#define D_EMB 1024
#define NH 16

#define MFMA16(a, b, c) __builtin_amdgcn_mfma_f32_16x16x32_bf16((a), (b), (c), 0, 0, 0)

__device__ __forceinline__ void gld16(void* lds, const void* g) {
  __builtin_amdgcn_global_load_lds(
      (__attribute__((address_space(1))) void*)(void*)(g),
      (__attribute__((address_space(3))) void*)(lds), 16, 0, 0);
}

__device__ __forceinline__ float exp2_hw(float x) {
  float r;
  asm("v_exp_f32 %0, %1" : "=v"(r) : "v"(x));
  return r;
}

// ---------------- fp32 -> bf16 convert ----------------
__global__ __launch_bounds__(256) void cvt_bf16(const float* __restrict__ in,
                                                bf16_t* __restrict__ out, int n4) {
  int i = blockIdx.x * 256 + threadIdx.x;
  if (i >= n4) return;
  float4 v = ((const float4*)in)[i];
  bf16x4 o;
  o[0] = (bf16_t)v.x; o[1] = (bf16_t)v.y; o[2] = (bf16_t)v.z; o[3] = (bf16_t)v.w;
  ((bf16x4*)out)[i] = o;
}

// ============ QKV GEMM: 256x192 tile, single-buffer, FULLY CO-RESIDENT =========
// Packing fix (round 22): grid 32x16 = 512 blocks; LDS = 32KB(A)+24KB(W) = 56KB
// single-buffered -> 2 blocks/CU -> ALL 512 blocks resident (zero dispatch tail),
// 16 waves/CU (4/SIMD) -> m97-style implicit wave-level overlap hides the
// 2-barrier convoy (m114). 8 waves 2Mx4N: wave tile 128x48, acc[8][3] (96 AGPR).
// Loop: stage(t) -> barrier (drains vmcnt+lgkm: tile in LDS) -> compute(t) ->
// barrier (all reads serviced before next overwrite). Proven round-9 pattern.
// Epilogue: qkv scatter (V keys permuted within 32-blocks; Q scaled by log2e/8).
__global__ __launch_bounds__(512, 2) void gemm_qkv_sb(
    const bf16_t* __restrict__ A, const bf16_t* __restrict__ W,
    const float* __restrict__ bias, bf16_t* __restrict__ outQ) {
  const int K = 1024;
  __shared__ __attribute__((aligned(16))) bf16_t As[256 * 64];  // 32KB
  __shared__ __attribute__((aligned(16))) bf16_t Ws[192 * 64];  // 24KB
  const int tid = threadIdx.x, lane = tid & 63, wid = tid >> 6;
  const int l15 = lane & 15, lg = lane >> 4;
  const int wm = wid >> 2, wn = wid & 3;  // 2M x 4N
  int lin = blockIdx.x + 16 * blockIdx.y;  // grid (16, 32): 512 blocks
  lin = (lin & 7) * 64 + (lin >> 3);       // XCD swizzle (bijective, 512%8==0)
  const int tm = (lin >> 4) * 256, tn = (lin & 15) * 192;
  const int q0 = tid * 16;

  auto stage = [&](int kt) {
#pragma unroll
    for (int i = 0; i < 4; ++i) {  // A: 32KB
      int q = q0 + i * 8192;
      int row = q >> 7;  // 0..255
      int scb = (q & 127) ^ ((row & 7) << 4);
      gld16((char*)As + (q & ~1023),
            (const char*)A + ((size_t)(tm + row) * K + kt * 64) * 2 + scb);
    }
#pragma unroll
    for (int i = 0; i < 3; ++i) {  // W: 24KB
      int q = q0 + i * 8192;
      int row = q >> 7;  // 0..191
      int scb = (q & 127) ^ ((row & 7) << 4);
      gld16((char*)Ws + (q & ~1023),
            (const char*)W + ((size_t)(tn + row) * K + kt * 64) * 2 + scb);
    }
  };

  f32x4 acc[8][3] = {};

  for (int kt = 0; kt < 16; ++kt) {
    stage(kt);
    __syncthreads();  // implicit vmcnt(0)+lgkmcnt(0): tile staged
#pragma unroll
    for (int kk = 0; kk < 2; ++kk) {
      const int cb = kk * 64 + lg * 16;
      bf16x8 bfr[3];
#pragma unroll
      for (int ni = 0; ni < 3; ++ni) {
        int col = wn * 48 + ni * 16 + l15;
        bfr[ni] = *(const bf16x8*)((const char*)Ws + col * 128 +
                                   (cb ^ ((col & 7) << 4)));
      }
#pragma unroll
      for (int mh = 0; mh < 2; ++mh) {
        bf16x8 af[4];
#pragma unroll
        for (int m2 = 0; m2 < 4; ++m2) {
          int row = wm * 128 + mh * 64 + m2 * 16 + l15;
          af[m2] = *(const bf16x8*)((const char*)As + row * 128 +
                                    (cb ^ ((row & 7) << 4)));
        }
        __builtin_amdgcn_s_setprio(1);
#pragma unroll
        for (int m2 = 0; m2 < 4; ++m2)
#pragma unroll
          for (int ni = 0; ni < 3; ++ni)
            acc[mh * 4 + m2][ni] = MFMA16(af[m2], bfr[ni], acc[mh * 4 + m2][ni]);
        __builtin_amdgcn_s_setprio(0);
      }
    }
    if (kt < 15) __syncthreads();  // all reads serviced before next overwrite
  }

  // epilogue: qkv scatter (V keys permuted within 32-blocks for attn b128 PV)
#pragma unroll
  for (int mi = 0; mi < 8; ++mi)
#pragma unroll
    for (int ni = 0; ni < 3; ++ni) {
      int e = tn + wn * 48 + ni * 16 + l15;
      float bv = bias[e];
      int h = e / 192;
      int r = e - h * 192;
      int tt = r >> 6, c = r & 63;
#pragma unroll
      for (int j = 0; j < 4; ++j) {
        int m = tm + wm * 128 + mi * 16 + lg * 4 + j;
        int b = m >> 11, s = m & 2047;
        float v = acc[mi][ni][j] + bv;
        if (tt == 0) v *= 0.18033688011112042f;  // (1/sqrt(64)) * log2(e)
        size_t base = ((size_t)(b * NH + h) * 3 + tt) * (size_t)(S_LEN * 64);
        size_t idx;
        if (tt == 2) {
          int rs = s & 31;
          int rp = (((rs >> 2) & 3) << 3) | ((rs >> 4) << 2) | (rs & 3);
          idx = base + (size_t)c * S_LEN + (size_t)((s & ~31) | rp);
        } else {
          idx = base + (size_t)s * 64 + c;
        }
        outQ[idx] = (bf16_t)v;
      }
    }
}

// ---------------- GEMM (round-18 dbuf version; used for out-proj only) ----------
template <int EPI>
__global__ __launch_bounds__(256) void gemm_bt(
    const bf16_t* __restrict__ A, const bf16_t* __restrict__ W,
    const float* __restrict__ bias, float* __restrict__ outF,
    bf16_t* __restrict__ outQ, int M, int N, int K) {
  __shared__ __attribute__((aligned(16))) bf16_t As[2][128 * 64];
  __shared__ __attribute__((aligned(16))) bf16_t Ws[2][128 * 64];
  const int tid = threadIdx.x;
  const int lane = tid & 63;
  const int wid = tid >> 6;
  const int l15 = lane & 15, lg = lane >> 4;
  int lin = blockIdx.x + gridDim.x * blockIdx.y;
  const int nwg = gridDim.x * gridDim.y;
  lin = (lin & 7) * (nwg >> 3) + (lin >> 3);  // XCD swizzle (bijective, nwg%8==0)
  const int tm = (lin / gridDim.x) * 128, tn = (lin % gridDim.x) * 128;
  const int wm = (wid >> 1) * 64, wn = (wid & 1) * 64;
  f32x4 acc[4][4] = {};
  const int q0 = tid * 16;

  auto stage = [&](int k0, int buf) {
#pragma unroll
    for (int i = 0; i < 4; ++i) {
      int q = q0 + i * 4096;
      int row = q >> 7;
      int scb = (q & 127) ^ ((row & 7) << 4);
      gld16((char*)As[buf] + (q & ~1023),
            (const char*)A + ((size_t)(tm + row) * K + k0) * 2 + scb);
      gld16((char*)Ws[buf] + (q & ~1023),
            (const char*)W + ((size_t)(tn + row) * K + k0) * 2 + scb);
    }
  };

  stage(0, 0);
  __syncthreads();

  const int nkt = K >> 6;
  for (int it = 0; it < nkt; ++it) {
    const int cur = it & 1;
    if (it + 1 < nkt) stage((it + 1) << 6, cur ^ 1);
#pragma unroll
    for (int kk = 0; kk < 2; ++kk) {
      const int cb = kk * 64 + lg * 16;
      bf16x8 af[4], bfr[4];
#pragma unroll
      for (int mi = 0; mi < 4; ++mi) {
        int row = wm + mi * 16 + l15;
        af[mi] = *(const bf16x8*)((const char*)As[cur] + row * 128 +
                                  (cb ^ ((row & 7) << 4)));
      }
#pragma unroll
      for (int ni = 0; ni < 4; ++ni) {
        int row = wn + ni * 16 + l15;
        bfr[ni] = *(const bf16x8*)((const char*)Ws[cur] + row * 128 +
                                   (cb ^ ((row & 7) << 4)));
      }
#pragma unroll
      for (int mi = 0; mi < 4; ++mi)
#pragma unroll
        for (int ni = 0; ni < 4; ++ni)
          acc[mi][ni] = MFMA16(af[mi], bfr[ni], acc[mi][ni]);
    }
    if (it + 1 < nkt) __syncthreads();
  }

  if (EPI == 0) {
#pragma unroll
    for (int mi = 0; mi < 4; ++mi)
#pragma unroll
      for (int ni = 0; ni < 4; ++ni) {
        int colg = tn + wn + ni * 16 + l15;
        float bv = bias[colg];
#pragma unroll
        for (int j = 0; j < 4; ++j) {
          int rowg = tm + wm + mi * 16 + lg * 4 + j;
          outF[(size_t)rowg * N + colg] = acc[mi][ni][j] + bv;
        }
      }
  } else {
#pragma unroll
    for (int mi = 0; mi < 4; ++mi)
#pragma unroll
      for (int ni = 0; ni < 4; ++ni) {
        int e = tn + wn + ni * 16 + l15;
        float bv = bias[e];
        int h = e / 192;
        int r = e - h * 192;
        int t = r >> 6, c = r & 63;
#pragma unroll
        for (int j = 0; j < 4; ++j) {
          int m = tm + wm + mi * 16 + lg * 4 + j;
          int b = m >> 11, s = m & 2047;
          float v = acc[mi][ni][j] + bv;
          if (t == 0) v *= 0.18033688011112042f;
          size_t base = ((size_t)(b * NH + h) * 3 + t) * (size_t)(S_LEN * 64);
          size_t idx;
          if (t == 2) {
            int rs = s & 31;
            int rp = (((rs >> 2) & 3) << 3) | ((rs >> 4) << 2) | (rs & 3);
            idx = base + (size_t)c * S_LEN + (size_t)((s & ~31) | rp);
          } else {
            idx = base + (size_t)s * 64 + c;
          }
          outQ[idx] = (bf16_t)v;
        }
      }
  }
}

// ---------------- Flash attention: 64 q-rows/wave, T15 pipeline, MFMA denom ------
// (round-17 verbatim — passing at 4.88e-4)
__global__ __launch_bounds__(256, 2) void attn_fwd(const bf16_t* __restrict__ qkvb,
                                                   bf16_t* __restrict__ attnb) {
  __shared__ __attribute__((aligned(16))) bf16_t Ks[3][64 * 64];
  __shared__ __attribute__((aligned(16))) bf16_t Vs[3][64 * 64];  // V^T tile [d][key']
  const int tid = threadIdx.x, lane = tid & 63, wid = tid >> 6;
  const int l15 = lane & 15, lg = lane >> 4;
  int lin = blockIdx.x + (blockIdx.y << 3);   // grid (8,64): 512 blocks
  lin = (lin & 7) * 64 + (lin >> 3);          // XCD swizzle (bijective)
  const int qt = lin & 7;
  const int bh = lin >> 3;
  const int b = bh >> 4, h = bh & 15;
  const char* Qg = (const char*)qkvb + (size_t)bh * 3 * (S_LEN * 64) * 2;
  const char* Kg = Qg + (size_t)S_LEN * 64 * 2;
  const char* Vtg = Kg + (size_t)S_LEN * 64 * 2;
  const int q0 = tid * 16;

  bf16x8 qf[4][2];
#pragma unroll
  for (int mi = 0; mi < 4; ++mi) {
    const char* qr = Qg + (size_t)(qt * 256 + wid * 64 + mi * 16 + l15) * 128;
#pragma unroll
    for (int kb = 0; kb < 2; ++kb)
      qf[mi][kb] = *(const bf16x8*)(qr + kb * 64 + lg * 16);
  }

  auto stageK = [&](int t) {
#pragma unroll
    for (int i = 0; i < 2; ++i) {
      int q = q0 + i * 4096;
      int row = q >> 7;
      int scb = (q & 127) ^ ((row & 7) << 4);
      gld16((char*)Ks[t % 3] + (q & ~1023), Kg + (size_t)(t * 64 + row) * 128 + scb);
    }
  };
  auto stageV = [&](int t) {
#pragma unroll
    for (int i = 0; i < 2; ++i) {
      int q = q0 + i * 4096;
      int row = q >> 7;
      int scb = (q & 127) ^ ((row & 7) << 4);
      gld16((char*)Vs[t % 3] + (q & ~1023),
            Vtg + (size_t)row * (S_LEN * 2) + t * 128 + scb);
    }
  };

  f32x4 o[4][4] = {};
  f32x4 den[4] = {};
  bf16x8 pf[2][4];
  bf16x8 onesf;
#pragma unroll
  for (int j = 0; j < 8; ++j) onesf[j] = (bf16_t)1.0f;
  const int swk = (l15 & 7) << 4;

  auto QK = [&](const bf16_t* Kc, f32x4(&stv)[4][4]) {
#pragma unroll
    for (int nk = 0; nk < 4; ++nk) {
      const char* kr = (const char*)Kc + (nk * 16 + l15) * 128;
      bf16x8 kf0 = *(const bf16x8*)(kr + ((lg * 16) ^ swk));
      bf16x8 kf1 = *(const bf16x8*)(kr + ((64 + lg * 16) ^ swk));
#pragma unroll
      for (int mi = 0; mi < 4; ++mi) {
        f32x4 z = {};
        z = MFMA16(kf0, qf[mi][0], z);
        stv[mi][nk] = MFMA16(kf1, qf[mi][1], z);
      }
    }
  };
  auto SM = [&](f32x4(&stv)[4][4]) {
#pragma unroll
    for (int mi = 0; mi < 4; ++mi)
#pragma unroll
      for (int nk = 0; nk < 4; ++nk)
#pragma unroll
        for (int j = 0; j < 4; ++j)
          stv[mi][nk][j] = exp2_hw(stv[mi][nk][j]);
#pragma unroll
    for (int kp = 0; kp < 2; ++kp)
#pragma unroll
      for (int mi = 0; mi < 4; ++mi)
#pragma unroll
        for (int j = 0; j < 4; ++j) {
          pf[kp][mi][j] = (bf16_t)stv[mi][2 * kp][j];
          pf[kp][mi][4 + j] = (bf16_t)stv[mi][2 * kp + 1][j];
        }
  };
  auto PV = [&](const bf16_t* Vc) {
#pragma unroll
    for (int kp = 0; kp < 2; ++kp) {
#pragma unroll
      for (int ndv = 0; ndv < 4; ++ndv) {
        const char* vr = (const char*)Vc + (ndv * 16 + l15) * 128;
        bf16x8 vf = *(const bf16x8*)(vr + ((kp * 64 + 16 * lg) ^ swk));
#pragma unroll
        for (int mi = 0; mi < 4; ++mi)
          o[mi][ndv] = MFMA16(pf[kp][mi], vf, o[mi][ndv]);
      }
#pragma unroll
      for (int mi = 0; mi < 4; ++mi)
        den[mi] = MFMA16(pf[kp][mi], onesf, den[mi]);
    }
  };

  stageV(0); stageK(0); stageV(1); stageK(1); stageK(2);
  asm volatile("s_waitcnt vmcnt(6)" ::: "memory");
  __builtin_amdgcn_s_barrier();
  asm volatile("" ::: "memory");
  {
    f32x4 stv[4][4];
    __builtin_amdgcn_s_setprio(1);
    QK(Ks[0], stv);
    __builtin_amdgcn_s_setprio(0);
    SM(stv);
  }

  for (int kt = 0; kt < 30; ++kt) {
    asm volatile("s_waitcnt vmcnt(2)" ::: "memory");
    __builtin_amdgcn_s_barrier();
    asm volatile("" ::: "memory");
    stageV(kt + 2);
    if (kt + 3 < 32) stageK(kt + 3);
    f32x4 stv[4][4];
    __builtin_amdgcn_s_setprio(1);
    QK(Ks[(kt + 1) % 3], stv);
    PV(Vs[kt % 3]);
    __builtin_amdgcn_s_setprio(0);
    SM(stv);
  }
  asm volatile("s_waitcnt vmcnt(0)" ::: "memory");
  __builtin_amdgcn_s_barrier();
  asm volatile("" ::: "memory");
  {
    f32x4 stv[4][4];
    __builtin_amdgcn_s_setprio(1);
    QK(Ks[31 % 3], stv);
    PV(Vs[30 % 3]);
    __builtin_amdgcn_s_setprio(0);
    SM(stv);
  }
  PV(Vs[31 % 3]);

  float inv[4][4];
#pragma unroll
  for (int mi = 0; mi < 4; ++mi)
#pragma unroll
    for (int j = 0; j < 4; ++j)
      inv[mi][j] = 1.0f / den[mi][j];

#pragma unroll
  for (int mi = 0; mi < 4; ++mi)
#pragma unroll
    for (int j = 0; j < 4; ++j) {
      int srow = qt * 256 + wid * 64 + mi * 16 + lg * 4 + j;
      bf16_t* dst = attnb + ((size_t)b * S_LEN + srow) * D_EMB + h * 64;
#pragma unroll
      for (int ndv = 0; ndv < 4; ++ndv)
        dst[ndv * 16 + l15] = (bf16_t)(o[mi][ndv][j] * inv[mi][j]);
    }
}

// ---------------- launch ----------------
extern "C" void kernel_launch(void* const* d_in, const int* in_sizes, int n_in,
                              void* d_out, int out_size, void* d_ws, size_t ws_size,
                              hipStream_t stream) {
  const float* x = (const float*)d_in[0];
  const float* w_qkv = (const float*)d_in[1];
  const float* b_qkv = (const float*)d_in[2];
  const float* w_out = (const float*)d_in[3];
  const float* b_out = (const float*)d_in[4];
  float* out = (float*)d_out;

  bf16_t* xb = (bf16_t*)d_ws;            // 8388608 elems
  bf16_t* wqkvb = xb + 8388608;          // 3145728
  bf16_t* woutb = wqkvb + 3145728;       // 1048576
  bf16_t* qkvb = woutb + 1048576;        // 25165824 ([B][H][3][...])
  bf16_t* attnb = qkvb + 25165824;       // 8388608  (total ~92.3 MB)

  cvt_bf16<<<8192, 256, 0, stream>>>(x, xb, 2097152);
  cvt_bf16<<<3072, 256, 0, stream>>>(w_qkv, wqkvb, 786432);
  cvt_bf16<<<1024, 256, 0, stream>>>(w_out, woutb, 262144);

  gemm_qkv_sb<<<dim3(16, 32), 512, 0, stream>>>(xb, wqkvb, b_qkv, qkvb);
  attn_fwd<<<dim3(8, 64), 256, 0, stream>>>(qkvb, attnb);
  gemm_bt<0><<<dim3(8, 64), 256, 0, stream>>>(attnb, woutb, b_out, out, nullptr,
                                              8192, 1024, 1024);
}